// Round 10
// baseline (2200.649 us; speedup 1.0000x reference)
//
#include <hip/hip_runtime.h>
#include <math.h>

#define NN 100000
#define NE 3200000
#define XD 2000
#define HID 128
#define NC 20

#define FEAT_OFF  ((size_t)NN * NC)                    // 2,000,000
#define OFEAT_OFF (FEAT_OFF + (size_t)NN * HID)        // 14,800,000

// ws layout (bytes)
#define WS_FLAG    0
#define WS_WNHAT   256
#define WS_CNT     16384                // int[NN]  (float deg in fallback)
#define WS_ROWS    417792               // int[NN+1]  (BT in fallback)
#define WS_CURSOR  819200               // int[NN]
#define WS_BSUM    1220608              // int[128]
#define WS_CSR     1245184              // int[NE]   (BT lives here pre-fill)
#define WS_HB      14045184             // bf16[NN*HID] relu(feat)
#define WS_NEEDED  (WS_HB + (size_t)NN * HID * 2 + 1024)

#define NB_SCAN 98                      // ceil(NN/1024)
#define KPAD 2016                       // 63 K-steps of 32
#define KSTEPS 63

typedef __attribute__((ext_vector_type(8))) short bf16x8;
typedef __attribute__((ext_vector_type(4))) float f32x4;

__device__ inline unsigned short f2bf(float f) {
    unsigned u = __builtin_bit_cast(unsigned, f);
    unsigned r = (u + 0x7fffu + ((u >> 16) & 1u)) >> 16;
    return (unsigned short)r;
}
__device__ inline float bf2f(unsigned short h) {
    return __builtin_bit_cast(float, ((unsigned)h) << 16);
}

// ---------------------------------------------------------------------------
__global__ void detect_idx_kernel(const unsigned* __restrict__ ei, int* __restrict__ flag) {
    if (threadIdx.x == 0) {
        bool hz = true;
        for (int i = 0; i < 16; ++i) hz = hz && (ei[2 * i + 1] == 0u);
        *flag = hz ? 1 : 0;
    }
}

__global__ void wn_norm_kernel(const float* __restrict__ Wn, float* __restrict__ WnHat) {
    int c = threadIdx.x;
    if (c >= NC) return;
    float s = 0.f;
    for (int k = 0; k < HID; ++k) { float w = Wn[k * NC + c]; s = fmaf(w, w, s); }
    float inv = 1.f / fmaxf(sqrtf(s), 1e-12f);
    for (int k = 0; k < HID; ++k) WnHat[k * NC + c] = Wn[k * NC + c] * inv;
}

// ---------------------------------------------------------------------------
// W1 [XD][HID] fp32 -> BT bf16, K-step tiled: BT[(k>>5)*4096 + c*32 + (k&31)]
// ---------------------------------------------------------------------------
__global__ __launch_bounds__(256) void w1conv_kernel(const float* __restrict__ W1,
                                                     unsigned short* __restrict__ BT) {
    const int i = blockIdx.x * 256 + threadIdx.x;
    if (i >= KPAD * HID) return;
    const int k = i >> 7;
    const int c = i & 127;
    unsigned short v = 0;
    if (k < XD) v = f2bf(W1[(size_t)k * HID + c]);
    BT[(size_t)(k >> 5) * 4096 + c * 32 + (k & 31)] = v;
}

// ---------------------------------------------------------------------------
// GEMM1 (MFMA bf16, 2-phase double-buffered LDS) — R6-proven version.
// ---------------------------------------------------------------------------
__global__ __launch_bounds__(256) void gemm1_kernel(const float* __restrict__ x,
                                                    const unsigned short* __restrict__ BT,
                                                    const float* __restrict__ b1,
                                                    float* __restrict__ feat,
                                                    unsigned short* __restrict__ hb) {
    __shared__ unsigned short sA[2][128][56];
    __shared__ unsigned short sB[2][128][56];

    const int t = threadIdx.x;
    const int lane = t & 63;
    const int wid = t >> 6;
    const int wr = wid >> 1;
    const int wc = wid & 1;
    const int row0 = blockIdx.x * 128;

    const int srow = t >> 3;
    const int sk   = (t & 7) * 4;

    const int fr = lane & 15;
    const int fk = (lane >> 4) * 8;

    float bias[4];
#pragma unroll
    for (int j = 0; j < 4; ++j) bias[j] = b1[wc * 64 + j * 16 + fr];

    f32x4 acc[4][4];
#pragma unroll
    for (int i = 0; i < 4; ++i)
#pragma unroll
        for (int j = 0; j < 4; ++j) acc[i][j] = (f32x4)0.f;

    float4 xv[4];
    bf16x8 bv[2];

    // ---- prologue: load tile 0, stage into buffer 0 ----
    {
        const int gk = sk;
#pragma unroll
        for (int p = 0; p < 4; ++p) {
            const int gr = row0 + srow + p * 32;
            float4 v = make_float4(0.f, 0.f, 0.f, 0.f);
            if (gr < NN && gk < XD) v = *(const float4*)(x + (size_t)gr * XD + gk);
            xv[p] = v;
        }
#pragma unroll
        for (int p = 0; p < 2; ++p)
            bv[p] = *(const bf16x8*)(BT + (size_t)(t + p * 256) * 8);

#pragma unroll
        for (int p = 0; p < 4; ++p) {
            const unsigned short b0 = f2bf(xv[p].x), b1s = f2bf(xv[p].y);
            const unsigned short b2 = f2bf(xv[p].z), b3 = f2bf(xv[p].w);
            uint2 w;
            w.x = (unsigned)b0 | ((unsigned)b1s << 16);
            w.y = (unsigned)b2 | ((unsigned)b3 << 16);
            *(uint2*)&sA[0][srow + p * 32][sk] = w;
        }
#pragma unroll
        for (int p = 0; p < 2; ++p) {
            const int i = t + p * 256;
            *(bf16x8*)&sB[0][i >> 2][(i & 3) * 8] = bv[p];
        }
    }
    __syncthreads();   // tile 0 ready

    int cur = 0;
    for (int ks = 0; ks < KSTEPS; ++ks) {
        const bool more = (ks + 1 < KSTEPS);

        // ---- issue NEXT tile's global loads (in flight during MFMA) ----
        if (more) {
            const int gk = (ks + 1) * 32 + sk;
#pragma unroll
            for (int p = 0; p < 4; ++p) {
                const int gr = row0 + srow + p * 32;
                float4 v = make_float4(0.f, 0.f, 0.f, 0.f);
                if (gr < NN && gk < XD) v = *(const float4*)(x + (size_t)gr * XD + gk);
                xv[p] = v;
            }
            const unsigned short* bs = BT + (size_t)(ks + 1) * 4096;
#pragma unroll
            for (int p = 0; p < 2; ++p)
                bv[p] = *(const bf16x8*)(bs + (size_t)(t + p * 256) * 8);
        }

        // ---- fragments + MFMA from buffer cur ----
        {
            bf16x8 af[4], bfr[4];
#pragma unroll
            for (int i = 0; i < 4; ++i)
                af[i] = *(const bf16x8*)&sA[cur][wr * 64 + i * 16 + fr][fk];
#pragma unroll
            for (int j = 0; j < 4; ++j)
                bfr[j] = *(const bf16x8*)&sB[cur][wc * 64 + j * 16 + fr][fk];

#pragma unroll
            for (int i = 0; i < 4; ++i)
#pragma unroll
                for (int j = 0; j < 4; ++j)
                    acc[i][j] = __builtin_amdgcn_mfma_f32_16x16x32_bf16(af[i], bfr[j], acc[i][j], 0, 0, 0);
        }

        // ---- stage tile ks+1 into buffer cur^1; single barrier per step ----
        if (more) {
            const int nxt = cur ^ 1;
#pragma unroll
            for (int p = 0; p < 4; ++p) {
                const unsigned short b0 = f2bf(xv[p].x), b1s = f2bf(xv[p].y);
                const unsigned short b2 = f2bf(xv[p].z), b3 = f2bf(xv[p].w);
                uint2 w;
                w.x = (unsigned)b0 | ((unsigned)b1s << 16);
                w.y = (unsigned)b2 | ((unsigned)b3 << 16);
                *(uint2*)&sA[nxt][srow + p * 32][sk] = w;
            }
#pragma unroll
            for (int p = 0; p < 2; ++p) {
                const int i = t + p * 256;
                *(bf16x8*)&sB[nxt][i >> 2][(i & 3) * 8] = bv[p];
            }
            __syncthreads();
            cur = nxt;
        }
    }

    const int rb = row0 + wr * 64 + (lane >> 4) * 4;
    const int cb = wc * 64 + fr;
#pragma unroll
    for (int i = 0; i < 4; ++i) {
#pragma unroll
        for (int r = 0; r < 4; ++r) {
            const int row = rb + i * 16 + r;
            if (row < NN) {
#pragma unroll
                for (int j = 0; j < 4; ++j) {
                    const float v = acc[i][j][r] + bias[j];
                    feat[(size_t)row * HID + cb + j * 16] = v;
                    if (hb) hb[(size_t)row * HID + cb + j * 16] = f2bf(fmaxf(v, 0.f));
                }
            }
        }
    }
}

// ---------------------------------------------------------------------------
// CSR build: histogram, 3-step scan, fill
// ---------------------------------------------------------------------------
__global__ __launch_bounds__(256) void hist_kernel(const unsigned* __restrict__ ei,
                                                   const int* __restrict__ flag,
                                                   int* __restrict__ cnt) {
    const long long e = (long long)blockIdx.x * blockDim.x + threadIdx.x;
    if (e >= NE) return;
    const int f = *flag;
    const size_t di = f ? (size_t)(2 * ((long long)NE + e)) : (size_t)((long long)NE + e);
    atomicAdd(&cnt[ei[di]], 1);
}

__global__ __launch_bounds__(1024) void scan1_kernel(const int* __restrict__ cnt,
                                                     int* __restrict__ rs,
                                                     int* __restrict__ bsum) {
    __shared__ int sd[1024];
    const int t = threadIdx.x;
    const int i = blockIdx.x * 1024 + t;
    const int v = (i < NN) ? cnt[i] : 0;
    sd[t] = v;
    __syncthreads();
    for (int off = 1; off < 1024; off <<= 1) {
        const int u = (t >= off) ? sd[t - off] : 0;
        __syncthreads();
        sd[t] += u;
        __syncthreads();
    }
    if (i < NN) rs[i] = sd[t] - v;
    if (t == 1023) bsum[blockIdx.x] = sd[1023];
}

__global__ void scan2_kernel(int* __restrict__ bsum) {
    if (threadIdx.x == 0) {
        int run = 0;
        for (int b = 0; b < NB_SCAN; ++b) { const int x = bsum[b]; bsum[b] = run; run += x; }
    }
}

__global__ __launch_bounds__(1024) void scan3_kernel(int* __restrict__ rs,
                                                     int* __restrict__ cursor,
                                                     const int* __restrict__ bsum) {
    const int i = blockIdx.x * 1024 + threadIdx.x;
    if (i < NN) {
        const int v = rs[i] + bsum[i >> 10];
        rs[i] = v;
        cursor[i] = v;
    }
    if (i == 0) rs[NN] = NE;
}

__global__ __launch_bounds__(256) void fill_kernel(const unsigned* __restrict__ ei,
                                                   const int* __restrict__ flag,
                                                   int* __restrict__ cursor,
                                                   int* __restrict__ csr) {
    const long long e = (long long)blockIdx.x * blockDim.x + threadIdx.x;
    if (e >= NE) return;
    const int f = *flag;
    const size_t si = f ? (size_t)(2 * e)                    : (size_t)e;
    const size_t di = f ? (size_t)(2 * ((long long)NE + e))  : (size_t)((long long)NE + e);
    const unsigned src = ei[si];
    const unsigned dst = ei[di];
    const int pos = atomicAdd(&cursor[dst], 1);
    csr[pos] = (int)src;
}

// ---------------------------------------------------------------------------
// Gather (pull, bf16): agg[n] = mean_{j in N(n)} hb[src_j].  One wave/node.
// ---------------------------------------------------------------------------
__global__ __launch_bounds__(256) void gather_kernel(const int* __restrict__ rs,
                                                     const int* __restrict__ csr,
                                                     const unsigned short* __restrict__ hb,
                                                     float* __restrict__ agg) {
    const int lane = threadIdx.x & 63;
    const int gw = (blockIdx.x * 256 + threadIdx.x) >> 6;
    const int nw = gridDim.x * 4;
    const int o = lane * 2;

    for (int n = gw; n < NN; n += nw) {
        const int s = rs[n];
        const int e2 = rs[n + 1];
        float ax = 0.f, ay = 0.f;
        int j = s;
        for (; j + 4 <= e2; j += 4) {
            const int s0 = csr[j], s1 = csr[j + 1], s2 = csr[j + 2], s3 = csr[j + 3];
            const unsigned u0 = *(const unsigned*)(hb + (size_t)s0 * HID + o);
            const unsigned u1 = *(const unsigned*)(hb + (size_t)s1 * HID + o);
            const unsigned u2 = *(const unsigned*)(hb + (size_t)s2 * HID + o);
            const unsigned u3 = *(const unsigned*)(hb + (size_t)s3 * HID + o);
            ax += __builtin_bit_cast(float, u0 << 16) + __builtin_bit_cast(float, u1 << 16)
                + __builtin_bit_cast(float, u2 << 16) + __builtin_bit_cast(float, u3 << 16);
            ay += __builtin_bit_cast(float, u0 & 0xffff0000u) + __builtin_bit_cast(float, u1 & 0xffff0000u)
                + __builtin_bit_cast(float, u2 & 0xffff0000u) + __builtin_bit_cast(float, u3 & 0xffff0000u);
        }
        for (; j < e2; ++j) {
            const unsigned u = *(const unsigned*)(hb + (size_t)csr[j] * HID + o);
            ax += __builtin_bit_cast(float, u << 16);
            ay += __builtin_bit_cast(float, u & 0xffff0000u);
        }
        const float d = fmaxf((float)(e2 - s), 1.f);
        *(float2*)(agg + (size_t)n * HID + o) = make_float2(ax / d, ay / d);
    }
}

// ---------------------------------------------------------------------------
// Fallback scatter path (tiny ws)
// ---------------------------------------------------------------------------
__global__ __launch_bounds__(256) void scatter_kernel(const unsigned* __restrict__ ei,
                                                      const int* __restrict__ flag,
                                                      const float* __restrict__ feat,
                                                      float* __restrict__ msg,
                                                      float* __restrict__ deg) {
    const long long g = (long long)blockIdx.x * blockDim.x + threadIdx.x;
    const long long e = g >> 5;
    const int lane = (int)(g & 31);
    if (e >= NE) return;
    const int f = *flag;
    const size_t si = f ? (size_t)(2 * e)                   : (size_t)e;
    const size_t di = f ? (size_t)(2 * ((long long)NE + e)) : (size_t)((long long)NE + e);
    const unsigned src = ei[si];
    const unsigned dst = ei[di];
    float4 v = *(const float4*)(feat + (size_t)src * HID + lane * 4);
    float* m = msg + (size_t)dst * HID + lane * 4;
    atomicAdd(m + 0, fmaxf(v.x, 0.f));
    atomicAdd(m + 1, fmaxf(v.y, 0.f));
    atomicAdd(m + 2, fmaxf(v.z, 0.f));
    atomicAdd(m + 3, fmaxf(v.w, 0.f));
    if (lane == 0) atomicAdd(deg + dst, 1.0f);
}

__global__ __launch_bounds__(256) void divide_kernel(float* __restrict__ agg,
                                                     const float* __restrict__ deg) {
    const int i = blockIdx.x * 256 + threadIdx.x;
    if (i >= NN * (HID / 4)) return;
    const int n = i >> 5;
    const float d = fmaxf(deg[n], 1.0f);
    float4 v = ((float4*)agg)[i];
    v.x /= d; v.y /= d; v.z /= d; v.w /= d;
    ((float4*)agg)[i] = v;
}

// ---------------------------------------------------------------------------
// Combine (MFMA, hi/lo split) — R4-proven version, 256 threads.
// ---------------------------------------------------------------------------
__global__ __launch_bounds__(256) void combine_kernel(const float* __restrict__ Wl,
                                                      const float* __restrict__ bl,
                                                      const float* __restrict__ Wr,
                                                      const float* __restrict__ feat,
                                                      float* __restrict__ ofeat) {
    __shared__ unsigned short sB[2][128][256];   // [h/l][col][k] swizzled, 128 KB

    const int t = threadIdx.x;
    const int lane = t & 63;
    const int wv = t >> 6;

    for (int i = t; i < 256 * 128; i += 256) {
        const int k = i >> 7;
        const int c = i & 127;
        const float w = (k < 128) ? Wl[(size_t)k * 128 + c] : Wr[(size_t)(k - 128) * 128 + c];
        const unsigned short h = f2bf(w);
        const unsigned short lo = f2bf(w - bf2f(h));
        const int byte = (c * 512 + k * 2) ^ ((c & 7) << 4);
        *(unsigned short*)((char*)&sB[0][0][0] + byte) = h;
        *(unsigned short*)((char*)&sB[1][0][0] + byte) = lo;
    }
    __syncthreads();

    const int fr = lane & 15;
    const int fk = lane >> 4;          // 0..3
    float blv[8];
#pragma unroll
    for (int j = 0; j < 8; ++j) blv[j] = bl[j * 16 + fr];

    const int nch = (NN + 63) / 64;    // 1563
    for (int ch = blockIdx.x; ch < nch; ch += gridDim.x) {
        const int row = ch * 64 + wv * 16 + fr;
        const int rowc = (row < NN) ? row : (NN - 1);

        float4 araw[8][2];
#pragma unroll
        for (int s = 0; s < 8; ++s) {
            const int ks = s * 32 + fk * 8;
            const float* p = (s < 4) ? (ofeat + (size_t)rowc * HID + ks)
                                     : (feat + (size_t)rowc * HID + (ks - 128));
            float4 v0 = *(const float4*)(p);
            float4 v1 = *(const float4*)(p + 4);
            if (s >= 4) {
                v0.x = fmaxf(v0.x, 0.f); v0.y = fmaxf(v0.y, 0.f);
                v0.z = fmaxf(v0.z, 0.f); v0.w = fmaxf(v0.w, 0.f);
                v1.x = fmaxf(v1.x, 0.f); v1.y = fmaxf(v1.y, 0.f);
                v1.z = fmaxf(v1.z, 0.f); v1.w = fmaxf(v1.w, 0.f);
            }
            araw[s][0] = v0; araw[s][1] = v1;
        }

        f32x4 acc[8];
#pragma unroll
        for (int j = 0; j < 8; ++j) { acc[j][0] = blv[j]; acc[j][1] = blv[j]; acc[j][2] = blv[j]; acc[j][3] = blv[j]; }

#pragma unroll
        for (int s = 0; s < 8; ++s) {
            float av[8] = {araw[s][0].x, araw[s][0].y, araw[s][0].z, araw[s][0].w,
                           araw[s][1].x, araw[s][1].y, araw[s][1].z, araw[s][1].w};
            bf16x8 ah, al;
#pragma unroll
            for (int q = 0; q < 8; ++q) {
                const unsigned short h = f2bf(av[q]);
                ah[q] = (short)h;
                al[q] = (short)f2bf(av[q] - bf2f(h));
            }
            const int kb = (s * 32 + fk * 8) * 2;
#pragma unroll
            for (int j = 0; j < 8; ++j) {
                const int col = j * 16 + fr;
                const int byte = (col * 512 + kb) ^ ((col & 7) << 4);
                const bf16x8 bh = *(const bf16x8*)((const char*)&sB[0][0][0] + byte);
                const bf16x8 blo = *(const bf16x8*)((const char*)&sB[1][0][0] + byte);
                acc[j] = __builtin_amdgcn_mfma_f32_16x16x32_bf16(ah, bh, acc[j], 0, 0, 0);
                acc[j] = __builtin_amdgcn_mfma_f32_16x16x32_bf16(al, bh, acc[j], 0, 0, 0);
                acc[j] = __builtin_amdgcn_mfma_f32_16x16x32_bf16(ah, blo, acc[j], 0, 0, 0);
            }
        }

        const int rb = ch * 64 + wv * 16 + fk * 4;
#pragma unroll
        for (int r = 0; r < 4; ++r) {
            const int rowo = rb + r;
            if (rowo < NN) {
#pragma unroll
                for (int j = 0; j < 8; ++j)
                    ofeat[(size_t)rowo * HID + j * 16 + fr] = acc[j][r];
            }
        }
    }
}

// ---------------------------------------------------------------------------
// Out: out = 10 * rownorm(out_feat) @ WnHat.  32 nodes per tile.
// ---------------------------------------------------------------------------
__global__ __launch_bounds__(256) void out_kernel(const float* __restrict__ ofeat,
                                                  const float* __restrict__ WnHat,
                                                  float* __restrict__ out) {
    __shared__ float sWn[HID][NC];
    __shared__ float sRow[32][HID];
    __shared__ float sPs[32][8];
    __shared__ float sScale[32];

    const int t = threadIdx.x;
    for (int i = t; i < HID * NC; i += 256) ((float*)sWn)[i] = WnHat[i];

    const int ntile = NN / 32;   // 3125 exact
    for (int tb = blockIdx.x; tb < ntile; tb += gridDim.x) {
        const int base = tb * 32;
        __syncthreads();
        for (int i = t; i < 32 * 32; i += 256) {
            const int n = i >> 5;
            const int q = (i & 31) * 4;
            *(float4*)&sRow[n][q] = *(const float4*)(ofeat + (size_t)(base + n) * HID + q);
        }
        __syncthreads();
        {
            const int n = t >> 3, seg = t & 7;
            float s = 0.f;
#pragma unroll
            for (int q = 0; q < 16; ++q) { const float v = sRow[n][seg * 16 + q]; s = fmaf(v, v, s); }
            sPs[n][seg] = s;
        }
        __syncthreads();
        if (t < 32) {
            float s = 0.f;
#pragma unroll
            for (int q = 0; q < 8; ++q) s += sPs[t][q];
            sScale[t] = 10.f / fmaxf(sqrtf(s), 1e-12f);
        }
        __syncthreads();
        for (int i = t; i < 32 * NC; i += 256) {
            const int n = i / NC;
            const int c = i % NC;
            float s = 0.f;
            for (int k = 0; k < HID; ++k) s = fmaf(sRow[n][k], sWn[k][c], s);
            out[(size_t)(base + n) * NC + c] = sScale[n] * s;
        }
    }
}

// ---------------------------------------------------------------------------
extern "C" void kernel_launch(void* const* d_in, const int* in_sizes, int n_in,
                              void* d_out, int out_size, void* d_ws, size_t ws_size,
                              hipStream_t stream) {
    const float*    x  = (const float*)d_in[0];
    const unsigned* ei = (const unsigned*)d_in[1];
    const float*    W1 = (const float*)d_in[2];
    const float*    b1 = (const float*)d_in[3];
    const float*    Wl = (const float*)d_in[4];
    const float*    bl = (const float*)d_in[5];
    const float*    Wr = (const float*)d_in[6];
    const float*    Wn = (const float*)d_in[7];

    float* out   = (float*)d_out;
    float* feat  = out + FEAT_OFF;
    float* ofeat = out + OFEAT_OFF;

    char* ws = (char*)d_ws;
    int*   flag   = (int*)(ws + WS_FLAG);
    float* WnHat  = (float*)(ws + WS_WNHAT);
    int*   cnt    = (int*)(ws + WS_CNT);
    int*   rs     = (int*)(ws + WS_ROWS);
    int*   cursor = (int*)(ws + WS_CURSOR);
    int*   bsum   = (int*)(ws + WS_BSUM);
    int*   csr    = (int*)(ws + WS_CSR);

    const bool big_ws = (ws_size >= WS_NEEDED);
    unsigned short* BT = (unsigned short*)(big_ws ? (void*)csr : (void*)(ws + WS_ROWS));
    unsigned short* hb = big_ws ? (unsigned short*)(ws + WS_HB) : (unsigned short*)0;

    detect_idx_kernel<<<1, 64, 0, stream>>>(ei, flag);
    wn_norm_kernel<<<1, 32, 0, stream>>>(Wn, WnHat);
    w1conv_kernel<<<(KPAD * HID + 255) / 256, 256, 0, stream>>>(W1, BT);

    gemm1_kernel<<<(NN + 127) / 128, 256, 0, stream>>>(x, BT, b1, feat, hb);

    if (big_ws) {
        // MEASUREMENT: CSR-build group runs 4x (idempotent as a group; BT is
        // dead after gemm1). csr_us = (dur_us - baseline_954) / 3.
        for (int rep = 0; rep < 4; ++rep) {
            hipMemsetAsync(cnt, 0, (size_t)NN * sizeof(int), stream);
            hist_kernel<<<(NE + 255) / 256, 256, 0, stream>>>(ei, flag, cnt);
            scan1_kernel<<<NB_SCAN, 1024, 0, stream>>>(cnt, rs, bsum);
            scan2_kernel<<<1, 64, 0, stream>>>(bsum);
            scan3_kernel<<<NB_SCAN, 1024, 0, stream>>>(rs, cursor, bsum);
            fill_kernel<<<(NE + 255) / 256, 256, 0, stream>>>(ei, flag, cursor, csr);
        }
        gather_kernel<<<2048, 256, 0, stream>>>(rs, csr, hb, ofeat);
    } else {
        float* deg = (float*)(ws + WS_CNT);
        hipMemsetAsync(ofeat, 0, (size_t)NN * HID * sizeof(float), stream);
        hipMemsetAsync(deg, 0, (size_t)NN * sizeof(float), stream);
        scatter_kernel<<<(int)(((long long)NE * 32) / 256), 256, 0, stream>>>(ei, flag, feat, ofeat, deg);
        divide_kernel<<<(NN * (HID / 4) + 255) / 256, 256, 0, stream>>>(ofeat, deg);
    }

    combine_kernel<<<256, 256, 0, stream>>>(Wl, bl, Wr, feat, ofeat);
    out_kernel<<<512, 256, 0, stream>>>(ofeat, WnHat, out);
}

// Round 11
// 641.705 us; speedup vs baseline: 3.4294x; 3.4294x over previous
//
#include <hip/hip_runtime.h>
#include <math.h>

#define NN 100000
#define NE 3200000
#define XD 2000
#define HID 128
#define NC 20

#define FEAT_OFF  ((size_t)NN * NC)                    // 2,000,000
#define OFEAT_OFF (FEAT_OFF + (size_t)NN * HID)        // 14,800,000

// ws layout (bytes)
#define WS_FLAG    0
#define WS_WNHAT   256
#define WS_CNT     16384                // float deg (fallback path only)
#define WS_ROWS    417792               // int[NN+1] rs   (BT in fallback)
#define WS_PARTIAL 819200               // int[196*256] bucket partials (200.7 KB)
#define WS_BSUM    1220608              // int[64] scan block sums
#define WS_CSR     1245184              // int[NE] csr    (BT lives here pre-build)
#define WS_HB      14045184             // bf16[NN*HID] relu(feat)
#define WS_PAIRS   39645184             // uint2[NE] (src,dst) bucket-grouped
#define WS_NEEDED  (WS_PAIRS + (size_t)NE * 8 + 1024)

#define KPAD 2016                       // 63 K-steps of 32
#define KSTEPS 63

#define NBKT   196                      // buckets of 512 nodes (dst>>9)
#define NBLK0  256                      // edge-chunk blocks
#define CHUNK0 (NE / NBLK0)             // 12500, exact
#define NPART  (NBKT * NBLK0)           // 50176 = 49*1024, exact
#define NB_P   49                       // scan blocks for partials

typedef __attribute__((ext_vector_type(8))) short bf16x8;
typedef __attribute__((ext_vector_type(4))) float f32x4;

__device__ inline unsigned short f2bf(float f) {
    unsigned u = __builtin_bit_cast(unsigned, f);
    unsigned r = (u + 0x7fffu + ((u >> 16) & 1u)) >> 16;
    return (unsigned short)r;
}
__device__ inline float bf2f(unsigned short h) {
    return __builtin_bit_cast(float, ((unsigned)h) << 16);
}

// ---------------------------------------------------------------------------
__global__ void detect_idx_kernel(const unsigned* __restrict__ ei, int* __restrict__ flag) {
    if (threadIdx.x == 0) {
        bool hz = true;
        for (int i = 0; i < 16; ++i) hz = hz && (ei[2 * i + 1] == 0u);
        *flag = hz ? 1 : 0;
    }
}

__global__ void wn_norm_kernel(const float* __restrict__ Wn, float* __restrict__ WnHat) {
    int c = threadIdx.x;
    if (c >= NC) return;
    float s = 0.f;
    for (int k = 0; k < HID; ++k) { float w = Wn[k * NC + c]; s = fmaf(w, w, s); }
    float inv = 1.f / fmaxf(sqrtf(s), 1e-12f);
    for (int k = 0; k < HID; ++k) WnHat[k * NC + c] = Wn[k * NC + c] * inv;
}

// ---------------------------------------------------------------------------
// W1 [XD][HID] fp32 -> BT bf16, K-step tiled: BT[(k>>5)*4096 + c*32 + (k&31)]
// ---------------------------------------------------------------------------
__global__ __launch_bounds__(256) void w1conv_kernel(const float* __restrict__ W1,
                                                     unsigned short* __restrict__ BT) {
    const int i = blockIdx.x * 256 + threadIdx.x;
    if (i >= KPAD * HID) return;
    const int k = i >> 7;
    const int c = i & 127;
    unsigned short v = 0;
    if (k < XD) v = f2bf(W1[(size_t)k * HID + c]);
    BT[(size_t)(k >> 5) * 4096 + c * 32 + (k & 31)] = v;
}

// ---------------------------------------------------------------------------
// GEMM1 (MFMA bf16, 2-phase double-buffered LDS) — R6-proven version.
// ---------------------------------------------------------------------------
__global__ __launch_bounds__(256) void gemm1_kernel(const float* __restrict__ x,
                                                    const unsigned short* __restrict__ BT,
                                                    const float* __restrict__ b1,
                                                    float* __restrict__ feat,
                                                    unsigned short* __restrict__ hb) {
    __shared__ unsigned short sA[2][128][56];
    __shared__ unsigned short sB[2][128][56];

    const int t = threadIdx.x;
    const int lane = t & 63;
    const int wid = t >> 6;
    const int wr = wid >> 1;
    const int wc = wid & 1;
    const int row0 = blockIdx.x * 128;

    const int srow = t >> 3;
    const int sk   = (t & 7) * 4;

    const int fr = lane & 15;
    const int fk = (lane >> 4) * 8;

    float bias[4];
#pragma unroll
    for (int j = 0; j < 4; ++j) bias[j] = b1[wc * 64 + j * 16 + fr];

    f32x4 acc[4][4];
#pragma unroll
    for (int i = 0; i < 4; ++i)
#pragma unroll
        for (int j = 0; j < 4; ++j) acc[i][j] = (f32x4)0.f;

    float4 xv[4];
    bf16x8 bv[2];

    {
        const int gk = sk;
#pragma unroll
        for (int p = 0; p < 4; ++p) {
            const int gr = row0 + srow + p * 32;
            float4 v = make_float4(0.f, 0.f, 0.f, 0.f);
            if (gr < NN && gk < XD) v = *(const float4*)(x + (size_t)gr * XD + gk);
            xv[p] = v;
        }
#pragma unroll
        for (int p = 0; p < 2; ++p)
            bv[p] = *(const bf16x8*)(BT + (size_t)(t + p * 256) * 8);

#pragma unroll
        for (int p = 0; p < 4; ++p) {
            const unsigned short b0 = f2bf(xv[p].x), b1s = f2bf(xv[p].y);
            const unsigned short b2 = f2bf(xv[p].z), b3 = f2bf(xv[p].w);
            uint2 w;
            w.x = (unsigned)b0 | ((unsigned)b1s << 16);
            w.y = (unsigned)b2 | ((unsigned)b3 << 16);
            *(uint2*)&sA[0][srow + p * 32][sk] = w;
        }
#pragma unroll
        for (int p = 0; p < 2; ++p) {
            const int i = t + p * 256;
            *(bf16x8*)&sB[0][i >> 2][(i & 3) * 8] = bv[p];
        }
    }
    __syncthreads();

    int cur = 0;
    for (int ks = 0; ks < KSTEPS; ++ks) {
        const bool more = (ks + 1 < KSTEPS);

        if (more) {
            const int gk = (ks + 1) * 32 + sk;
#pragma unroll
            for (int p = 0; p < 4; ++p) {
                const int gr = row0 + srow + p * 32;
                float4 v = make_float4(0.f, 0.f, 0.f, 0.f);
                if (gr < NN && gk < XD) v = *(const float4*)(x + (size_t)gr * XD + gk);
                xv[p] = v;
            }
            const unsigned short* bs = BT + (size_t)(ks + 1) * 4096;
#pragma unroll
            for (int p = 0; p < 2; ++p)
                bv[p] = *(const bf16x8*)(bs + (size_t)(t + p * 256) * 8);
        }

        {
            bf16x8 af[4], bfr[4];
#pragma unroll
            for (int i = 0; i < 4; ++i)
                af[i] = *(const bf16x8*)&sA[cur][wr * 64 + i * 16 + fr][fk];
#pragma unroll
            for (int j = 0; j < 4; ++j)
                bfr[j] = *(const bf16x8*)&sB[cur][wc * 64 + j * 16 + fr][fk];

#pragma unroll
            for (int i = 0; i < 4; ++i)
#pragma unroll
                for (int j = 0; j < 4; ++j)
                    acc[i][j] = __builtin_amdgcn_mfma_f32_16x16x32_bf16(af[i], bfr[j], acc[i][j], 0, 0, 0);
        }

        if (more) {
            const int nxt = cur ^ 1;
#pragma unroll
            for (int p = 0; p < 4; ++p) {
                const unsigned short b0 = f2bf(xv[p].x), b1s = f2bf(xv[p].y);
                const unsigned short b2 = f2bf(xv[p].z), b3 = f2bf(xv[p].w);
                uint2 w;
                w.x = (unsigned)b0 | ((unsigned)b1s << 16);
                w.y = (unsigned)b2 | ((unsigned)b3 << 16);
                *(uint2*)&sA[nxt][srow + p * 32][sk] = w;
            }
#pragma unroll
            for (int p = 0; p < 2; ++p) {
                const int i = t + p * 256;
                *(bf16x8*)&sB[nxt][i >> 2][(i & 3) * 8] = bv[p];
            }
            __syncthreads();
            cur = nxt;
        }
    }

    const int rb = row0 + wr * 64 + (lane >> 4) * 4;
    const int cb = wc * 64 + fr;
#pragma unroll
    for (int i = 0; i < 4; ++i) {
#pragma unroll
        for (int r = 0; r < 4; ++r) {
            const int row = rb + i * 16 + r;
            if (row < NN) {
#pragma unroll
                for (int j = 0; j < 4; ++j) {
                    const float v = acc[i][j][r] + bias[j];
                    feat[(size_t)row * HID + cb + j * 16] = v;
                    if (hb) hb[(size_t)row * HID + cb + j * 16] = f2bf(fmaxf(v, 0.f));
                }
            }
        }
    }
}

// ---------------------------------------------------------------------------
// Bucketed CSR build (no global atomics):
// P0 bhist -> scanA/B/C over partials -> P2 bscatter pairs -> P3 bbuild csr+rs
// ---------------------------------------------------------------------------
__global__ __launch_bounds__(256) void bhist_kernel(const unsigned* __restrict__ ei,
                                                    const int* __restrict__ flag,
                                                    int* __restrict__ partial) {
    __shared__ int h[NBKT];
    const int t = threadIdx.x;
    const int blk = blockIdx.x;
    if (t < NBKT) h[t] = 0;
    __syncthreads();
    const int f = *flag;
    const long long base = (long long)blk * CHUNK0;
    for (int k = t; k < CHUNK0; k += 256) {
        const long long e = base + k;
        const size_t di = f ? (size_t)(2 * ((long long)NE + e)) : (size_t)((long long)NE + e);
        atomicAdd(&h[ei[di] >> 9], 1);
    }
    __syncthreads();
    if (t < NBKT) partial[t * NBLK0 + blk] = h[t];
}

__global__ __launch_bounds__(1024) void scanA_kernel(int* __restrict__ data,
                                                     int* __restrict__ bsum, int n) {
    __shared__ int sd[1024];
    const int t = threadIdx.x;
    const int i = blockIdx.x * 1024 + t;
    const int v = (i < n) ? data[i] : 0;
    sd[t] = v;
    __syncthreads();
    for (int off = 1; off < 1024; off <<= 1) {
        const int u = (t >= off) ? sd[t - off] : 0;
        __syncthreads();
        sd[t] += u;
        __syncthreads();
    }
    if (i < n) data[i] = sd[t] - v;        // exclusive within block
    if (t == 1023) bsum[blockIdx.x] = sd[1023];
}

__global__ void scanB_kernel(int* __restrict__ bsum, int nb) {
    const int lane = threadIdx.x;
    int v = (lane < nb) ? bsum[lane] : 0;
    const int orig = v;
#pragma unroll
    for (int off = 1; off < 64; off <<= 1) {
        const int u = __shfl_up(v, off, 64);
        if (lane >= off) v += u;
    }
    if (lane < nb) bsum[lane] = v - orig;  // exclusive block offsets
}

__global__ __launch_bounds__(1024) void scanC_kernel(int* __restrict__ data,
                                                     const int* __restrict__ bsum, int n) {
    const int i = blockIdx.x * 1024 + threadIdx.x;
    if (i < n) data[i] += bsum[i >> 10];
}

__global__ __launch_bounds__(256) void bscatter_kernel(const unsigned* __restrict__ ei,
                                                       const int* __restrict__ flag,
                                                       const int* __restrict__ scanned,
                                                       uint2* __restrict__ pairs) {
    __shared__ int cur[NBKT];
    const int t = threadIdx.x;
    const int blk = blockIdx.x;
    if (t < NBKT) cur[t] = scanned[t * NBLK0 + blk];
    __syncthreads();
    const int f = *flag;
    const long long base = (long long)blk * CHUNK0;
    for (int k = t; k < CHUNK0; k += 256) {
        const long long e = base + k;
        const size_t si = f ? (size_t)(2 * e)                   : (size_t)e;
        const size_t di = f ? (size_t)(2 * ((long long)NE + e)) : (size_t)((long long)NE + e);
        const unsigned src = ei[si];
        const unsigned dst = ei[di];
        const int pos = atomicAdd(&cur[dst >> 9], 1);
        pairs[pos] = make_uint2(src, dst);
    }
}

__global__ __launch_bounds__(512) void bbuild_kernel(const uint2* __restrict__ pairs,
                                                     const int* __restrict__ scanned,
                                                     int* __restrict__ rs,
                                                     int* __restrict__ csr) {
    __shared__ int cnt[512];
    __shared__ int sd[512];
    __shared__ int pos_[512];
    const int t = threadIdx.x;
    const int b = blockIdx.x;
    const int start = scanned[b * NBLK0];
    const int end = (b + 1 < NBKT) ? scanned[(b + 1) * NBLK0] : NE;

    cnt[t] = 0;
    __syncthreads();
    for (int j = start + t; j < end; j += 512)
        atomicAdd(&cnt[pairs[j].y & 511], 1);
    __syncthreads();

    sd[t] = cnt[t];
    __syncthreads();
    for (int off = 1; off < 512; off <<= 1) {
        const int u = (t >= off) ? sd[t - off] : 0;
        __syncthreads();
        sd[t] += u;
        __syncthreads();
    }
    const int p0 = start + sd[t] - cnt[t];   // exclusive
    pos_[t] = p0;
    const int node = b * 512 + t;
    if (node < NN) rs[node] = p0;
    if (b == NBKT - 1 && t == 0) rs[NN] = NE;
    __syncthreads();

    for (int j = start + t; j < end; j += 512) {
        const uint2 p = pairs[j];
        const int o = atomicAdd(&pos_[p.y & 511], 1);
        csr[o] = (int)p.x;
    }
}

// ---------------------------------------------------------------------------
// Gather (pull, bf16): agg[n] = mean_{j in N(n)} hb[src_j].  One wave/node.
// ---------------------------------------------------------------------------
__global__ __launch_bounds__(256) void gather_kernel(const int* __restrict__ rs,
                                                     const int* __restrict__ csr,
                                                     const unsigned short* __restrict__ hb,
                                                     float* __restrict__ agg) {
    const int lane = threadIdx.x & 63;
    const int gw = (blockIdx.x * 256 + threadIdx.x) >> 6;
    const int nw = gridDim.x * 4;
    const int o = lane * 2;

    for (int n = gw; n < NN; n += nw) {
        const int s = rs[n];
        const int e2 = rs[n + 1];
        float ax = 0.f, ay = 0.f;
        int j = s;
        for (; j + 4 <= e2; j += 4) {
            const int s0 = csr[j], s1 = csr[j + 1], s2 = csr[j + 2], s3 = csr[j + 3];
            const unsigned u0 = *(const unsigned*)(hb + (size_t)s0 * HID + o);
            const unsigned u1 = *(const unsigned*)(hb + (size_t)s1 * HID + o);
            const unsigned u2 = *(const unsigned*)(hb + (size_t)s2 * HID + o);
            const unsigned u3 = *(const unsigned*)(hb + (size_t)s3 * HID + o);
            ax += __builtin_bit_cast(float, u0 << 16) + __builtin_bit_cast(float, u1 << 16)
                + __builtin_bit_cast(float, u2 << 16) + __builtin_bit_cast(float, u3 << 16);
            ay += __builtin_bit_cast(float, u0 & 0xffff0000u) + __builtin_bit_cast(float, u1 & 0xffff0000u)
                + __builtin_bit_cast(float, u2 & 0xffff0000u) + __builtin_bit_cast(float, u3 & 0xffff0000u);
        }
        for (; j < e2; ++j) {
            const unsigned u = *(const unsigned*)(hb + (size_t)csr[j] * HID + o);
            ax += __builtin_bit_cast(float, u << 16);
            ay += __builtin_bit_cast(float, u & 0xffff0000u);
        }
        const float d = fmaxf((float)(e2 - s), 1.f);
        *(float2*)(agg + (size_t)n * HID + o) = make_float2(ax / d, ay / d);
    }
}

// ---------------------------------------------------------------------------
// Fallback scatter path (tiny ws)
// ---------------------------------------------------------------------------
__global__ __launch_bounds__(256) void scatter_kernel(const unsigned* __restrict__ ei,
                                                      const int* __restrict__ flag,
                                                      const float* __restrict__ feat,
                                                      float* __restrict__ msg,
                                                      float* __restrict__ deg) {
    const long long g = (long long)blockIdx.x * blockDim.x + threadIdx.x;
    const long long e = g >> 5;
    const int lane = (int)(g & 31);
    if (e >= NE) return;
    const int f = *flag;
    const size_t si = f ? (size_t)(2 * e)                   : (size_t)e;
    const size_t di = f ? (size_t)(2 * ((long long)NE + e)) : (size_t)((long long)NE + e);
    const unsigned src = ei[si];
    const unsigned dst = ei[di];
    float4 v = *(const float4*)(feat + (size_t)src * HID + lane * 4);
    float* m = msg + (size_t)dst * HID + lane * 4;
    atomicAdd(m + 0, fmaxf(v.x, 0.f));
    atomicAdd(m + 1, fmaxf(v.y, 0.f));
    atomicAdd(m + 2, fmaxf(v.z, 0.f));
    atomicAdd(m + 3, fmaxf(v.w, 0.f));
    if (lane == 0) atomicAdd(deg + dst, 1.0f);
}

__global__ __launch_bounds__(256) void divide_kernel(float* __restrict__ agg,
                                                     const float* __restrict__ deg) {
    const int i = blockIdx.x * 256 + threadIdx.x;
    if (i >= NN * (HID / 4)) return;
    const int n = i >> 5;
    const float d = fmaxf(deg[n], 1.0f);
    float4 v = ((float4*)agg)[i];
    v.x /= d; v.y /= d; v.z /= d; v.w /= d;
    ((float4*)agg)[i] = v;
}

// ---------------------------------------------------------------------------
// Combine (MFMA, hi/lo split) — R4-proven version, 256 threads.
// ---------------------------------------------------------------------------
__global__ __launch_bounds__(256) void combine_kernel(const float* __restrict__ Wl,
                                                      const float* __restrict__ bl,
                                                      const float* __restrict__ Wr,
                                                      const float* __restrict__ feat,
                                                      float* __restrict__ ofeat) {
    __shared__ unsigned short sB[2][128][256];   // [h/l][col][k] swizzled, 128 KB

    const int t = threadIdx.x;
    const int lane = t & 63;
    const int wv = t >> 6;

    for (int i = t; i < 256 * 128; i += 256) {
        const int k = i >> 7;
        const int c = i & 127;
        const float w = (k < 128) ? Wl[(size_t)k * 128 + c] : Wr[(size_t)(k - 128) * 128 + c];
        const unsigned short h = f2bf(w);
        const unsigned short lo = f2bf(w - bf2f(h));
        const int byte = (c * 512 + k * 2) ^ ((c & 7) << 4);
        *(unsigned short*)((char*)&sB[0][0][0] + byte) = h;
        *(unsigned short*)((char*)&sB[1][0][0] + byte) = lo;
    }
    __syncthreads();

    const int fr = lane & 15;
    const int fk = lane >> 4;          // 0..3
    float blv[8];
#pragma unroll
    for (int j = 0; j < 8; ++j) blv[j] = bl[j * 16 + fr];

    const int nch = (NN + 63) / 64;    // 1563
    for (int ch = blockIdx.x; ch < nch; ch += gridDim.x) {
        const int row = ch * 64 + wv * 16 + fr;
        const int rowc = (row < NN) ? row : (NN - 1);

        float4 araw[8][2];
#pragma unroll
        for (int s = 0; s < 8; ++s) {
            const int ks = s * 32 + fk * 8;
            const float* p = (s < 4) ? (ofeat + (size_t)rowc * HID + ks)
                                     : (feat + (size_t)rowc * HID + (ks - 128));
            float4 v0 = *(const float4*)(p);
            float4 v1 = *(const float4*)(p + 4);
            if (s >= 4) {
                v0.x = fmaxf(v0.x, 0.f); v0.y = fmaxf(v0.y, 0.f);
                v0.z = fmaxf(v0.z, 0.f); v0.w = fmaxf(v0.w, 0.f);
                v1.x = fmaxf(v1.x, 0.f); v1.y = fmaxf(v1.y, 0.f);
                v1.z = fmaxf(v1.z, 0.f); v1.w = fmaxf(v1.w, 0.f);
            }
            araw[s][0] = v0; araw[s][1] = v1;
        }

        f32x4 acc[8];
#pragma unroll
        for (int j = 0; j < 8; ++j) { acc[j][0] = blv[j]; acc[j][1] = blv[j]; acc[j][2] = blv[j]; acc[j][3] = blv[j]; }

#pragma unroll
        for (int s = 0; s < 8; ++s) {
            float av[8] = {araw[s][0].x, araw[s][0].y, araw[s][0].z, araw[s][0].w,
                           araw[s][1].x, araw[s][1].y, araw[s][1].z, araw[s][1].w};
            bf16x8 ah, al;
#pragma unroll
            for (int q = 0; q < 8; ++q) {
                const unsigned short h = f2bf(av[q]);
                ah[q] = (short)h;
                al[q] = (short)f2bf(av[q] - bf2f(h));
            }
            const int kb = (s * 32 + fk * 8) * 2;
#pragma unroll
            for (int j = 0; j < 8; ++j) {
                const int col = j * 16 + fr;
                const int byte = (col * 512 + kb) ^ ((col & 7) << 4);
                const bf16x8 bh = *(const bf16x8*)((const char*)&sB[0][0][0] + byte);
                const bf16x8 blo = *(const bf16x8*)((const char*)&sB[1][0][0] + byte);
                acc[j] = __builtin_amdgcn_mfma_f32_16x16x32_bf16(ah, bh, acc[j], 0, 0, 0);
                acc[j] = __builtin_amdgcn_mfma_f32_16x16x32_bf16(al, bh, acc[j], 0, 0, 0);
                acc[j] = __builtin_amdgcn_mfma_f32_16x16x32_bf16(ah, blo, acc[j], 0, 0, 0);
            }
        }

        const int rb = ch * 64 + wv * 16 + fk * 4;
#pragma unroll
        for (int r = 0; r < 4; ++r) {
            const int rowo = rb + r;
            if (rowo < NN) {
#pragma unroll
                for (int j = 0; j < 8; ++j)
                    ofeat[(size_t)rowo * HID + j * 16 + fr] = acc[j][r];
            }
        }
    }
}

// ---------------------------------------------------------------------------
// Out: out = 10 * rownorm(out_feat) @ WnHat.  32 nodes per tile.
// ---------------------------------------------------------------------------
__global__ __launch_bounds__(256) void out_kernel(const float* __restrict__ ofeat,
                                                  const float* __restrict__ WnHat,
                                                  float* __restrict__ out) {
    __shared__ float sWn[HID][NC];
    __shared__ float sRow[32][HID];
    __shared__ float sPs[32][8];
    __shared__ float sScale[32];

    const int t = threadIdx.x;
    for (int i = t; i < HID * NC; i += 256) ((float*)sWn)[i] = WnHat[i];

    const int ntile = NN / 32;   // 3125 exact
    for (int tb = blockIdx.x; tb < ntile; tb += gridDim.x) {
        const int base = tb * 32;
        __syncthreads();
        for (int i = t; i < 32 * 32; i += 256) {
            const int n = i >> 5;
            const int q = (i & 31) * 4;
            *(float4*)&sRow[n][q] = *(const float4*)(ofeat + (size_t)(base + n) * HID + q);
        }
        __syncthreads();
        {
            const int n = t >> 3, seg = t & 7;
            float s = 0.f;
#pragma unroll
            for (int q = 0; q < 16; ++q) { const float v = sRow[n][seg * 16 + q]; s = fmaf(v, v, s); }
            sPs[n][seg] = s;
        }
        __syncthreads();
        if (t < 32) {
            float s = 0.f;
#pragma unroll
            for (int q = 0; q < 8; ++q) s += sPs[t][q];
            sScale[t] = 10.f / fmaxf(sqrtf(s), 1e-12f);
        }
        __syncthreads();
        for (int i = t; i < 32 * NC; i += 256) {
            const int n = i / NC;
            const int c = i % NC;
            float s = 0.f;
            for (int k = 0; k < HID; ++k) s = fmaf(sRow[n][k], sWn[k][c], s);
            out[(size_t)(base + n) * NC + c] = sScale[n] * s;
        }
    }
}

// ---------------------------------------------------------------------------
extern "C" void kernel_launch(void* const* d_in, const int* in_sizes, int n_in,
                              void* d_out, int out_size, void* d_ws, size_t ws_size,
                              hipStream_t stream) {
    const float*    x  = (const float*)d_in[0];
    const unsigned* ei = (const unsigned*)d_in[1];
    const float*    W1 = (const float*)d_in[2];
    const float*    b1 = (const float*)d_in[3];
    const float*    Wl = (const float*)d_in[4];
    const float*    bl = (const float*)d_in[5];
    const float*    Wr = (const float*)d_in[6];
    const float*    Wn = (const float*)d_in[7];

    float* out   = (float*)d_out;
    float* feat  = out + FEAT_OFF;
    float* ofeat = out + OFEAT_OFF;

    char* ws = (char*)d_ws;
    int*   flag    = (int*)(ws + WS_FLAG);
    float* WnHat   = (float*)(ws + WS_WNHAT);
    int*   rs      = (int*)(ws + WS_ROWS);
    int*   partial = (int*)(ws + WS_PARTIAL);
    int*   bsum    = (int*)(ws + WS_BSUM);
    int*   csr     = (int*)(ws + WS_CSR);
    uint2* pairs   = (uint2*)(ws + WS_PAIRS);

    const bool big_ws = (ws_size >= WS_NEEDED);
    unsigned short* BT = (unsigned short*)(big_ws ? (void*)csr : (void*)(ws + WS_ROWS));
    unsigned short* hb = big_ws ? (unsigned short*)(ws + WS_HB) : (unsigned short*)0;

    detect_idx_kernel<<<1, 64, 0, stream>>>(ei, flag);
    wn_norm_kernel<<<1, 32, 0, stream>>>(Wn, WnHat);
    w1conv_kernel<<<(KPAD * HID + 255) / 256, 256, 0, stream>>>(W1, BT);

    gemm1_kernel<<<(NN + 127) / 128, 256, 0, stream>>>(x, BT, b1, feat, hb);

    if (big_ws) {
        // bucketed CSR build: no global atomics
        bhist_kernel<<<NBLK0, 256, 0, stream>>>(ei, flag, partial);
        scanA_kernel<<<NB_P, 1024, 0, stream>>>(partial, bsum, NPART);
        scanB_kernel<<<1, 64, 0, stream>>>(bsum, NB_P);
        scanC_kernel<<<NB_P, 1024, 0, stream>>>(partial, bsum, NPART);
        bscatter_kernel<<<NBLK0, 256, 0, stream>>>(ei, flag, partial, pairs);
        bbuild_kernel<<<NBKT, 512, 0, stream>>>(pairs, partial, rs, csr);
        gather_kernel<<<2048, 256, 0, stream>>>(rs, csr, hb, ofeat);
    } else {
        float* deg = (float*)(ws + WS_CNT);
        hipMemsetAsync(ofeat, 0, (size_t)NN * HID * sizeof(float), stream);
        hipMemsetAsync(deg, 0, (size_t)NN * sizeof(float), stream);
        scatter_kernel<<<(int)(((long long)NE * 32) / 256), 256, 0, stream>>>(ei, flag, feat, ofeat, deg);
        divide_kernel<<<(NN * (HID / 4) + 255) / 256, 256, 0, stream>>>(ofeat, deg);
    }

    combine_kernel<<<256, 256, 0, stream>>>(Wl, bl, Wr, feat, ofeat);
    out_kernel<<<512, 256, 0, stream>>>(ofeat, WnHat, out);
}

// Round 12
// 556.587 us; speedup vs baseline: 3.9538x; 1.1529x over previous
//
#include <hip/hip_runtime.h>
#include <math.h>

#define NN 100000
#define NE 3200000
#define XD 2000
#define HID 128
#define NC 20

#define FEAT_OFF  ((size_t)NN * NC)                    // 2,000,000
#define OFEAT_OFF (FEAT_OFF + (size_t)NN * HID)        // 14,800,000

// ws layout (bytes)
#define WS_FLAG    0
#define WS_WNHAT   256
#define WS_CNT     16384                // float deg (fallback path only)
#define WS_ROWS    417792               // int[NN+1] rs   (BT in fallback)
#define WS_PARTIAL 819200               // int[196*256] bucket partials (200.7 KB)
#define WS_BSUM    1220608              // int[64] scan block sums
#define WS_CSR     1245184              // int[NE] csr    (BT lives here pre-build)
#define WS_HB      14045184             // bf16[NN*HID] relu(feat)
#define WS_PAIRS   39645184             // uint2[NE] (src,dst) bucket-grouped
#define WS_NEEDED  (WS_PAIRS + (size_t)NE * 8 + 1024)

#define KPAD 2016                       // 63 K-steps of 32
#define KSTEPS 63

#define NBKT   196                      // buckets of 512 nodes (dst>>9)
#define NBLK0  256                      // edge-chunk blocks
#define CHUNK0 (NE / NBLK0)             // 12500, exact
#define NPART  (NBKT * NBLK0)           // 50176 = 49*1024, exact
#define NB_P   49                       // scan blocks for partials

typedef __attribute__((ext_vector_type(8))) short bf16x8;
typedef __attribute__((ext_vector_type(4))) float f32x4;

__device__ inline unsigned short f2bf(float f) {
    unsigned u = __builtin_bit_cast(unsigned, f);
    unsigned r = (u + 0x7fffu + ((u >> 16) & 1u)) >> 16;
    return (unsigned short)r;
}
__device__ inline float bf2f(unsigned short h) {
    return __builtin_bit_cast(float, ((unsigned)h) << 16);
}

// ---------------------------------------------------------------------------
__global__ void detect_idx_kernel(const unsigned* __restrict__ ei, int* __restrict__ flag) {
    if (threadIdx.x == 0) {
        bool hz = true;
        for (int i = 0; i < 16; ++i) hz = hz && (ei[2 * i + 1] == 0u);
        *flag = hz ? 1 : 0;
    }
}

__global__ void wn_norm_kernel(const float* __restrict__ Wn, float* __restrict__ WnHat) {
    int c = threadIdx.x;
    if (c >= NC) return;
    float s = 0.f;
    for (int k = 0; k < HID; ++k) { float w = Wn[k * NC + c]; s = fmaf(w, w, s); }
    float inv = 1.f / fmaxf(sqrtf(s), 1e-12f);
    for (int k = 0; k < HID; ++k) WnHat[k * NC + c] = Wn[k * NC + c] * inv;
}

// ---------------------------------------------------------------------------
// W1 [XD][HID] fp32 -> BT bf16, K-step tiled: BT[(k>>5)*4096 + c*32 + (k&31)]
// ---------------------------------------------------------------------------
__global__ __launch_bounds__(256) void w1conv_kernel(const float* __restrict__ W1,
                                                     unsigned short* __restrict__ BT) {
    const int i = blockIdx.x * 256 + threadIdx.x;
    if (i >= KPAD * HID) return;
    const int k = i >> 7;
    const int c = i & 127;
    unsigned short v = 0;
    if (k < XD) v = f2bf(W1[(size_t)k * HID + c]);
    BT[(size_t)(k >> 5) * 4096 + c * 32 + (k & 31)] = v;
}

// ---------------------------------------------------------------------------
// GEMM1 (MFMA bf16, 2-phase double-buffered LDS) — R6-proven version.
// ---------------------------------------------------------------------------
__global__ __launch_bounds__(256) void gemm1_kernel(const float* __restrict__ x,
                                                    const unsigned short* __restrict__ BT,
                                                    const float* __restrict__ b1,
                                                    float* __restrict__ feat,
                                                    unsigned short* __restrict__ hb) {
    __shared__ unsigned short sA[2][128][56];
    __shared__ unsigned short sB[2][128][56];

    const int t = threadIdx.x;
    const int lane = t & 63;
    const int wid = t >> 6;
    const int wr = wid >> 1;
    const int wc = wid & 1;
    const int row0 = blockIdx.x * 128;

    const int srow = t >> 3;
    const int sk   = (t & 7) * 4;

    const int fr = lane & 15;
    const int fk = (lane >> 4) * 8;

    float bias[4];
#pragma unroll
    for (int j = 0; j < 4; ++j) bias[j] = b1[wc * 64 + j * 16 + fr];

    f32x4 acc[4][4];
#pragma unroll
    for (int i = 0; i < 4; ++i)
#pragma unroll
        for (int j = 0; j < 4; ++j) acc[i][j] = (f32x4)0.f;

    float4 xv[4];
    bf16x8 bv[2];

    {
        const int gk = sk;
#pragma unroll
        for (int p = 0; p < 4; ++p) {
            const int gr = row0 + srow + p * 32;
            float4 v = make_float4(0.f, 0.f, 0.f, 0.f);
            if (gr < NN && gk < XD) v = *(const float4*)(x + (size_t)gr * XD + gk);
            xv[p] = v;
        }
#pragma unroll
        for (int p = 0; p < 2; ++p)
            bv[p] = *(const bf16x8*)(BT + (size_t)(t + p * 256) * 8);

#pragma unroll
        for (int p = 0; p < 4; ++p) {
            const unsigned short b0 = f2bf(xv[p].x), b1s = f2bf(xv[p].y);
            const unsigned short b2 = f2bf(xv[p].z), b3 = f2bf(xv[p].w);
            uint2 w;
            w.x = (unsigned)b0 | ((unsigned)b1s << 16);
            w.y = (unsigned)b2 | ((unsigned)b3 << 16);
            *(uint2*)&sA[0][srow + p * 32][sk] = w;
        }
#pragma unroll
        for (int p = 0; p < 2; ++p) {
            const int i = t + p * 256;
            *(bf16x8*)&sB[0][i >> 2][(i & 3) * 8] = bv[p];
        }
    }
    __syncthreads();

    int cur = 0;
    for (int ks = 0; ks < KSTEPS; ++ks) {
        const bool more = (ks + 1 < KSTEPS);

        if (more) {
            const int gk = (ks + 1) * 32 + sk;
#pragma unroll
            for (int p = 0; p < 4; ++p) {
                const int gr = row0 + srow + p * 32;
                float4 v = make_float4(0.f, 0.f, 0.f, 0.f);
                if (gr < NN && gk < XD) v = *(const float4*)(x + (size_t)gr * XD + gk);
                xv[p] = v;
            }
            const unsigned short* bs = BT + (size_t)(ks + 1) * 4096;
#pragma unroll
            for (int p = 0; p < 2; ++p)
                bv[p] = *(const bf16x8*)(bs + (size_t)(t + p * 256) * 8);
        }

        {
            bf16x8 af[4], bfr[4];
#pragma unroll
            for (int i = 0; i < 4; ++i)
                af[i] = *(const bf16x8*)&sA[cur][wr * 64 + i * 16 + fr][fk];
#pragma unroll
            for (int j = 0; j < 4; ++j)
                bfr[j] = *(const bf16x8*)&sB[cur][wc * 64 + j * 16 + fr][fk];

#pragma unroll
            for (int i = 0; i < 4; ++i)
#pragma unroll
                for (int j = 0; j < 4; ++j)
                    acc[i][j] = __builtin_amdgcn_mfma_f32_16x16x32_bf16(af[i], bfr[j], acc[i][j], 0, 0, 0);
        }

        if (more) {
            const int nxt = cur ^ 1;
#pragma unroll
            for (int p = 0; p < 4; ++p) {
                const unsigned short b0 = f2bf(xv[p].x), b1s = f2bf(xv[p].y);
                const unsigned short b2 = f2bf(xv[p].z), b3 = f2bf(xv[p].w);
                uint2 w;
                w.x = (unsigned)b0 | ((unsigned)b1s << 16);
                w.y = (unsigned)b2 | ((unsigned)b3 << 16);
                *(uint2*)&sA[nxt][srow + p * 32][sk] = w;
            }
#pragma unroll
            for (int p = 0; p < 2; ++p) {
                const int i = t + p * 256;
                *(bf16x8*)&sB[nxt][i >> 2][(i & 3) * 8] = bv[p];
            }
            __syncthreads();
            cur = nxt;
        }
    }

    const int rb = row0 + wr * 64 + (lane >> 4) * 4;
    const int cb = wc * 64 + fr;
#pragma unroll
    for (int i = 0; i < 4; ++i) {
#pragma unroll
        for (int r = 0; r < 4; ++r) {
            const int row = rb + i * 16 + r;
            if (row < NN) {
#pragma unroll
                for (int j = 0; j < 4; ++j) {
                    const float v = acc[i][j][r] + bias[j];
                    feat[(size_t)row * HID + cb + j * 16] = v;
                    if (hb) hb[(size_t)row * HID + cb + j * 16] = f2bf(fmaxf(v, 0.f));
                }
            }
        }
    }
}

// ---------------------------------------------------------------------------
// Bucketed CSR build (no global atomics):
// P0 bhist -> scanA/B/C over partials -> P2 bscatter pairs -> P3 bbuild csr+rs
// ---------------------------------------------------------------------------
__global__ __launch_bounds__(256) void bhist_kernel(const unsigned* __restrict__ ei,
                                                    const int* __restrict__ flag,
                                                    int* __restrict__ partial) {
    __shared__ int h[NBKT];
    const int t = threadIdx.x;
    const int blk = blockIdx.x;
    if (t < NBKT) h[t] = 0;
    __syncthreads();
    const int f = *flag;
    const long long base = (long long)blk * CHUNK0;
    for (int k = t; k < CHUNK0; k += 256) {
        const long long e = base + k;
        const size_t di = f ? (size_t)(2 * ((long long)NE + e)) : (size_t)((long long)NE + e);
        atomicAdd(&h[ei[di] >> 9], 1);
    }
    __syncthreads();
    if (t < NBKT) partial[t * NBLK0 + blk] = h[t];
}

__global__ __launch_bounds__(1024) void scanA_kernel(int* __restrict__ data,
                                                     int* __restrict__ bsum, int n) {
    __shared__ int sd[1024];
    const int t = threadIdx.x;
    const int i = blockIdx.x * 1024 + t;
    const int v = (i < n) ? data[i] : 0;
    sd[t] = v;
    __syncthreads();
    for (int off = 1; off < 1024; off <<= 1) {
        const int u = (t >= off) ? sd[t - off] : 0;
        __syncthreads();
        sd[t] += u;
        __syncthreads();
    }
    if (i < n) data[i] = sd[t] - v;        // exclusive within block
    if (t == 1023) bsum[blockIdx.x] = sd[1023];
}

__global__ void scanB_kernel(int* __restrict__ bsum, int nb) {
    const int lane = threadIdx.x;
    int v = (lane < nb) ? bsum[lane] : 0;
    const int orig = v;
#pragma unroll
    for (int off = 1; off < 64; off <<= 1) {
        const int u = __shfl_up(v, off, 64);
        if (lane >= off) v += u;
    }
    if (lane < nb) bsum[lane] = v - orig;  // exclusive block offsets
}

__global__ __launch_bounds__(1024) void scanC_kernel(int* __restrict__ data,
                                                     const int* __restrict__ bsum, int n) {
    const int i = blockIdx.x * 1024 + threadIdx.x;
    if (i < n) data[i] += bsum[i >> 10];
}

__global__ __launch_bounds__(256) void bscatter_kernel(const unsigned* __restrict__ ei,
                                                       const int* __restrict__ flag,
                                                       const int* __restrict__ scanned,
                                                       uint2* __restrict__ pairs) {
    __shared__ int cur[NBKT];
    const int t = threadIdx.x;
    const int blk = blockIdx.x;
    if (t < NBKT) cur[t] = scanned[t * NBLK0 + blk];
    __syncthreads();
    const int f = *flag;
    const long long base = (long long)blk * CHUNK0;
    for (int k = t; k < CHUNK0; k += 256) {
        const long long e = base + k;
        const size_t si = f ? (size_t)(2 * e)                   : (size_t)e;
        const size_t di = f ? (size_t)(2 * ((long long)NE + e)) : (size_t)((long long)NE + e);
        const unsigned src = ei[si];
        const unsigned dst = ei[di];
        const int pos = atomicAdd(&cur[dst >> 9], 1);
        pairs[pos] = make_uint2(src, dst);
    }
}

__global__ __launch_bounds__(512) void bbuild_kernel(const uint2* __restrict__ pairs,
                                                     const int* __restrict__ scanned,
                                                     int* __restrict__ rs,
                                                     int* __restrict__ csr) {
    __shared__ int cnt[512];
    __shared__ int sd[512];
    __shared__ int pos_[512];
    const int t = threadIdx.x;
    const int b = blockIdx.x;
    const int start = scanned[b * NBLK0];
    const int end = (b + 1 < NBKT) ? scanned[(b + 1) * NBLK0] : NE;

    cnt[t] = 0;
    __syncthreads();
    for (int j = start + t; j < end; j += 512)
        atomicAdd(&cnt[pairs[j].y & 511], 1);
    __syncthreads();

    sd[t] = cnt[t];
    __syncthreads();
    for (int off = 1; off < 512; off <<= 1) {
        const int u = (t >= off) ? sd[t - off] : 0;
        __syncthreads();
        sd[t] += u;
        __syncthreads();
    }
    const int p0 = start + sd[t] - cnt[t];   // exclusive
    pos_[t] = p0;
    const int node = b * 512 + t;
    if (node < NN) rs[node] = p0;
    if (b == NBKT - 1 && t == 0) rs[NN] = NE;
    __syncthreads();

    for (int j = start + t; j < end; j += 512) {
        const uint2 p = pairs[j];
        const int o = atomicAdd(&pos_[p.y & 511], 1);
        csr[o] = (int)p.x;
    }
}

// ---------------------------------------------------------------------------
// Gather (pull, bf16): agg[n] = mean_{j in N(n)} hb[src_j].  One wave/node.
// ---------------------------------------------------------------------------
__global__ __launch_bounds__(256) void gather_kernel(const int* __restrict__ rs,
                                                     const int* __restrict__ csr,
                                                     const unsigned short* __restrict__ hb,
                                                     float* __restrict__ agg) {
    const int lane = threadIdx.x & 63;
    const int gw = (blockIdx.x * 256 + threadIdx.x) >> 6;
    const int nw = gridDim.x * 4;
    const int o = lane * 2;

    for (int n = gw; n < NN; n += nw) {
        const int s = rs[n];
        const int e2 = rs[n + 1];
        float ax = 0.f, ay = 0.f;
        int j = s;
        for (; j + 4 <= e2; j += 4) {
            const int s0 = csr[j], s1 = csr[j + 1], s2 = csr[j + 2], s3 = csr[j + 3];
            const unsigned u0 = *(const unsigned*)(hb + (size_t)s0 * HID + o);
            const unsigned u1 = *(const unsigned*)(hb + (size_t)s1 * HID + o);
            const unsigned u2 = *(const unsigned*)(hb + (size_t)s2 * HID + o);
            const unsigned u3 = *(const unsigned*)(hb + (size_t)s3 * HID + o);
            ax += __builtin_bit_cast(float, u0 << 16) + __builtin_bit_cast(float, u1 << 16)
                + __builtin_bit_cast(float, u2 << 16) + __builtin_bit_cast(float, u3 << 16);
            ay += __builtin_bit_cast(float, u0 & 0xffff0000u) + __builtin_bit_cast(float, u1 & 0xffff0000u)
                + __builtin_bit_cast(float, u2 & 0xffff0000u) + __builtin_bit_cast(float, u3 & 0xffff0000u);
        }
        for (; j < e2; ++j) {
            const unsigned u = *(const unsigned*)(hb + (size_t)csr[j] * HID + o);
            ax += __builtin_bit_cast(float, u << 16);
            ay += __builtin_bit_cast(float, u & 0xffff0000u);
        }
        const float d = fmaxf((float)(e2 - s), 1.f);
        *(float2*)(agg + (size_t)n * HID + o) = make_float2(ax / d, ay / d);
    }
}

// ---------------------------------------------------------------------------
// Fallback scatter path (tiny ws)
// ---------------------------------------------------------------------------
__global__ __launch_bounds__(256) void scatter_kernel(const unsigned* __restrict__ ei,
                                                      const int* __restrict__ flag,
                                                      const float* __restrict__ feat,
                                                      float* __restrict__ msg,
                                                      float* __restrict__ deg) {
    const long long g = (long long)blockIdx.x * blockDim.x + threadIdx.x;
    const long long e = g >> 5;
    const int lane = (int)(g & 31);
    if (e >= NE) return;
    const int f = *flag;
    const size_t si = f ? (size_t)(2 * e)                   : (size_t)e;
    const size_t di = f ? (size_t)(2 * ((long long)NE + e)) : (size_t)((long long)NE + e);
    const unsigned src = ei[si];
    const unsigned dst = ei[di];
    float4 v = *(const float4*)(feat + (size_t)src * HID + lane * 4);
    float* m = msg + (size_t)dst * HID + lane * 4;
    atomicAdd(m + 0, fmaxf(v.x, 0.f));
    atomicAdd(m + 1, fmaxf(v.y, 0.f));
    atomicAdd(m + 2, fmaxf(v.z, 0.f));
    atomicAdd(m + 3, fmaxf(v.w, 0.f));
    if (lane == 0) atomicAdd(deg + dst, 1.0f);
}

__global__ __launch_bounds__(256) void divide_kernel(float* __restrict__ agg,
                                                     const float* __restrict__ deg) {
    const int i = blockIdx.x * 256 + threadIdx.x;
    if (i >= NN * (HID / 4)) return;
    const int n = i >> 5;
    const float d = fmaxf(deg[n], 1.0f);
    float4 v = ((float4*)agg)[i];
    v.x /= d; v.y /= d; v.z /= d; v.w /= d;
    ((float4*)agg)[i] = v;
}

// ---------------------------------------------------------------------------
// Combine v3 (MFMA, exact-A x bf16-B): out_feat = agg @ Wl + bl + relu(feat) @ Wr.
// B = [Wl;Wr] bf16-high only in 64 KB swizzled LDS -> 2 blocks/CU, 2 waves/SIMD.
// A split ah+al in-register: (Ah+Al)*Bh leaves only B's bf16 rounding (~0.2%).
// 2 MFMAs per (col,kstep). In-place over ofeat (per-row, no cross-block hazard).
// ---------------------------------------------------------------------------
__global__ __launch_bounds__(256) void combine_kernel(const float* __restrict__ Wl,
                                                      const float* __restrict__ bl,
                                                      const float* __restrict__ Wr,
                                                      const float* __restrict__ feat,
                                                      float* __restrict__ ofeat) {
    __shared__ unsigned short sB[128][256];   // [col][k] swizzled, 64 KB

    const int t = threadIdx.x;
    const int lane = t & 63;
    const int wv = t >> 6;

    for (int i = t; i < 256 * 128; i += 256) {
        const int k = i >> 7;
        const int c = i & 127;
        const float w = (k < 128) ? Wl[(size_t)k * 128 + c] : Wr[(size_t)(k - 128) * 128 + c];
        const int byte = (c * 512 + k * 2) ^ ((c & 7) << 4);
        *(unsigned short*)((char*)&sB[0][0] + byte) = f2bf(w);
    }
    __syncthreads();

    const int fr = lane & 15;
    const int fk = lane >> 4;          // 0..3
    float blv[8];
#pragma unroll
    for (int j = 0; j < 8; ++j) blv[j] = bl[j * 16 + fr];

    const int nch = (NN + 63) / 64;    // 1563
    for (int ch = blockIdx.x; ch < nch; ch += gridDim.x) {
        const int row = ch * 64 + wv * 16 + fr;
        const int rowc = (row < NN) ? row : (NN - 1);

        float4 araw[8][2];
#pragma unroll
        for (int s = 0; s < 8; ++s) {
            const int ks = s * 32 + fk * 8;
            const float* p = (s < 4) ? (ofeat + (size_t)rowc * HID + ks)
                                     : (feat + (size_t)rowc * HID + (ks - 128));
            float4 v0 = *(const float4*)(p);
            float4 v1 = *(const float4*)(p + 4);
            if (s >= 4) {
                v0.x = fmaxf(v0.x, 0.f); v0.y = fmaxf(v0.y, 0.f);
                v0.z = fmaxf(v0.z, 0.f); v0.w = fmaxf(v0.w, 0.f);
                v1.x = fmaxf(v1.x, 0.f); v1.y = fmaxf(v1.y, 0.f);
                v1.z = fmaxf(v1.z, 0.f); v1.w = fmaxf(v1.w, 0.f);
            }
            araw[s][0] = v0; araw[s][1] = v1;
        }

        f32x4 acc[8];
#pragma unroll
        for (int j = 0; j < 8; ++j) { acc[j][0] = blv[j]; acc[j][1] = blv[j]; acc[j][2] = blv[j]; acc[j][3] = blv[j]; }

#pragma unroll
        for (int s = 0; s < 8; ++s) {
            float av[8] = {araw[s][0].x, araw[s][0].y, araw[s][0].z, araw[s][0].w,
                           araw[s][1].x, araw[s][1].y, araw[s][1].z, araw[s][1].w};
            bf16x8 ah, al;
#pragma unroll
            for (int q = 0; q < 8; ++q) {
                const unsigned short h = f2bf(av[q]);
                ah[q] = (short)h;
                al[q] = (short)f2bf(av[q] - bf2f(h));
            }
            const int kb = (s * 32 + fk * 8) * 2;
#pragma unroll
            for (int j = 0; j < 8; ++j) {
                const int col = j * 16 + fr;
                const int byte = (col * 512 + kb) ^ ((col & 7) << 4);
                const bf16x8 bh = *(const bf16x8*)((const char*)&sB[0][0] + byte);
                acc[j] = __builtin_amdgcn_mfma_f32_16x16x32_bf16(ah, bh, acc[j], 0, 0, 0);
                acc[j] = __builtin_amdgcn_mfma_f32_16x16x32_bf16(al, bh, acc[j], 0, 0, 0);
            }
        }

        const int rb = ch * 64 + wv * 16 + fk * 4;
#pragma unroll
        for (int r = 0; r < 4; ++r) {
            const int rowo = rb + r;
            if (rowo < NN) {
#pragma unroll
                for (int j = 0; j < 8; ++j)
                    ofeat[(size_t)rowo * HID + j * 16 + fr] = acc[j][r];
            }
        }
    }
}

// ---------------------------------------------------------------------------
// Out: out = 10 * rownorm(out_feat) @ WnHat.  32 nodes per tile.
// ---------------------------------------------------------------------------
__global__ __launch_bounds__(256) void out_kernel(const float* __restrict__ ofeat,
                                                  const float* __restrict__ WnHat,
                                                  float* __restrict__ out) {
    __shared__ float sWn[HID][NC];
    __shared__ float sRow[32][HID];
    __shared__ float sPs[32][8];
    __shared__ float sScale[32];

    const int t = threadIdx.x;
    for (int i = t; i < HID * NC; i += 256) ((float*)sWn)[i] = WnHat[i];

    const int ntile = NN / 32;   // 3125 exact
    for (int tb = blockIdx.x; tb < ntile; tb += gridDim.x) {
        const int base = tb * 32;
        __syncthreads();
        for (int i = t; i < 32 * 32; i += 256) {
            const int n = i >> 5;
            const int q = (i & 31) * 4;
            *(float4*)&sRow[n][q] = *(const float4*)(ofeat + (size_t)(base + n) * HID + q);
        }
        __syncthreads();
        {
            const int n = t >> 3, seg = t & 7;
            float s = 0.f;
#pragma unroll
            for (int q = 0; q < 16; ++q) { const float v = sRow[n][seg * 16 + q]; s = fmaf(v, v, s); }
            sPs[n][seg] = s;
        }
        __syncthreads();
        if (t < 32) {
            float s = 0.f;
#pragma unroll
            for (int q = 0; q < 8; ++q) s += sPs[t][q];
            sScale[t] = 10.f / fmaxf(sqrtf(s), 1e-12f);
        }
        __syncthreads();
        for (int i = t; i < 32 * NC; i += 256) {
            const int n = i / NC;
            const int c = i % NC;
            float s = 0.f;
            for (int k = 0; k < HID; ++k) s = fmaf(sRow[n][k], sWn[k][c], s);
            out[(size_t)(base + n) * NC + c] = sScale[n] * s;
        }
    }
}

// ---------------------------------------------------------------------------
extern "C" void kernel_launch(void* const* d_in, const int* in_sizes, int n_in,
                              void* d_out, int out_size, void* d_ws, size_t ws_size,
                              hipStream_t stream) {
    const float*    x  = (const float*)d_in[0];
    const unsigned* ei = (const unsigned*)d_in[1];
    const float*    W1 = (const float*)d_in[2];
    const float*    b1 = (const float*)d_in[3];
    const float*    Wl = (const float*)d_in[4];
    const float*    bl = (const float*)d_in[5];
    const float*    Wr = (const float*)d_in[6];
    const float*    Wn = (const float*)d_in[7];

    float* out   = (float*)d_out;
    float* feat  = out + FEAT_OFF;
    float* ofeat = out + OFEAT_OFF;

    char* ws = (char*)d_ws;
    int*   flag    = (int*)(ws + WS_FLAG);
    float* WnHat   = (float*)(ws + WS_WNHAT);
    int*   rs      = (int*)(ws + WS_ROWS);
    int*   partial = (int*)(ws + WS_PARTIAL);
    int*   bsum    = (int*)(ws + WS_BSUM);
    int*   csr     = (int*)(ws + WS_CSR);
    uint2* pairs   = (uint2*)(ws + WS_PAIRS);

    const bool big_ws = (ws_size >= WS_NEEDED);
    unsigned short* BT = (unsigned short*)(big_ws ? (void*)csr : (void*)(ws + WS_ROWS));
    unsigned short* hb = big_ws ? (unsigned short*)(ws + WS_HB) : (unsigned short*)0;

    detect_idx_kernel<<<1, 64, 0, stream>>>(ei, flag);
    wn_norm_kernel<<<1, 32, 0, stream>>>(Wn, WnHat);
    w1conv_kernel<<<(KPAD * HID + 255) / 256, 256, 0, stream>>>(W1, BT);

    gemm1_kernel<<<(NN + 127) / 128, 256, 0, stream>>>(x, BT, b1, feat, hb);

    if (big_ws) {
        bhist_kernel<<<NBLK0, 256, 0, stream>>>(ei, flag, partial);
        scanA_kernel<<<NB_P, 1024, 0, stream>>>(partial, bsum, NPART);
        scanB_kernel<<<1, 64, 0, stream>>>(bsum, NB_P);
        scanC_kernel<<<NB_P, 1024, 0, stream>>>(partial, bsum, NPART);
        bscatter_kernel<<<NBLK0, 256, 0, stream>>>(ei, flag, partial, pairs);
        bbuild_kernel<<<NBKT, 512, 0, stream>>>(pairs, partial, rs, csr);
        gather_kernel<<<2048, 256, 0, stream>>>(rs, csr, hb, ofeat);
    } else {
        float* deg = (float*)(ws + WS_CNT);
        hipMemsetAsync(ofeat, 0, (size_t)NN * HID * sizeof(float), stream);
        hipMemsetAsync(deg, 0, (size_t)NN * sizeof(float), stream);
        scatter_kernel<<<(int)(((long long)NE * 32) / 256), 256, 0, stream>>>(ei, flag, feat, ofeat, deg);
        divide_kernel<<<(NN * (HID / 4) + 255) / 256, 256, 0, stream>>>(ofeat, deg);
    }

    combine_kernel<<<512, 256, 0, stream>>>(Wl, bl, Wr, feat, ofeat);
    out_kernel<<<512, 256, 0, stream>>>(ofeat, WnHat, out);
}